// Round 1
// 2532.499 us; speedup vs baseline: 1.1322x; 1.1322x over previous
//
#include <hip/hip_runtime.h>
#include <hip/hip_bf16.h>
#include <math.h>

#define N_NODES 16384
#define V_DIM   16384
#define E_EDGES 524288
#define H_HEADS 8
#define D_HEAD  64
#define EMB_DIM 16
#define NCLASS  40
#define ALPHA   0.2f
#define LN_EPS  1e-5f

__device__ __forceinline__ float warp_reduce_sum64(float v) {
#pragma unroll
    for (int m = 32; m >= 1; m >>= 1) v += __shfl_xor(v, m, 64);
    return v;
}

// ---------------------------------------------------------------- rowptr (CSR)
__global__ void build_rowptr(const int* __restrict__ row, int* __restrict__ rp) {
    int i = blockIdx.x * blockDim.x + threadIdx.x;
    if (i > E_EDGES) return;
    if (i == 0) {
        int r0 = row[0];
        for (int r = 0; r <= r0; ++r) rp[r] = 0;
    } else if (i == E_EDGES) {
        int rl = row[E_EDGES - 1];
        for (int r = rl + 1; r <= N_NODES; ++r) rp[r] = E_EDGES;
    } else {
        int ra = row[i - 1], rb = row[i];
        for (int r = ra + 1; r <= rb; ++r) rp[r] = i;
    }
}

// ------------------------------------------------- hot = x_in @ emb  (N x 16)
// wave handles 4 rows; lanes split K; 64 accumulators/lane; emb via float4 (L1/L2)
__global__ __launch_bounds__(256) void gemm_emb(const float* __restrict__ X,
                                                const float* __restrict__ Eb,
                                                float* __restrict__ hot) {
    const int lane = threadIdx.x & 63;
    const int wv   = threadIdx.x >> 6;
    const int rbase = blockIdx.x * 16 + wv * 4;
    float acc[4][16];
#pragma unroll
    for (int r = 0; r < 4; ++r)
#pragma unroll
        for (int j = 0; j < 16; ++j) acc[r][j] = 0.f;
    const float* xr0 = X + (size_t)rbase * V_DIM;
    for (int v0 = 0; v0 < V_DIM; v0 += 64) {
        int v = v0 + lane;
        float4 e0 = *(const float4*)(Eb + (size_t)v * 16 + 0);
        float4 e1 = *(const float4*)(Eb + (size_t)v * 16 + 4);
        float4 e2 = *(const float4*)(Eb + (size_t)v * 16 + 8);
        float4 e3 = *(const float4*)(Eb + (size_t)v * 16 + 12);
        float xv[4];
#pragma unroll
        for (int r = 0; r < 4; ++r) xv[r] = xr0[(size_t)r * V_DIM + v];
#pragma unroll
        for (int r = 0; r < 4; ++r) {
            float x = xv[r];
            acc[r][0]  = fmaf(x, e0.x, acc[r][0]);
            acc[r][1]  = fmaf(x, e0.y, acc[r][1]);
            acc[r][2]  = fmaf(x, e0.z, acc[r][2]);
            acc[r][3]  = fmaf(x, e0.w, acc[r][3]);
            acc[r][4]  = fmaf(x, e1.x, acc[r][4]);
            acc[r][5]  = fmaf(x, e1.y, acc[r][5]);
            acc[r][6]  = fmaf(x, e1.z, acc[r][6]);
            acc[r][7]  = fmaf(x, e1.w, acc[r][7]);
            acc[r][8]  = fmaf(x, e2.x, acc[r][8]);
            acc[r][9]  = fmaf(x, e2.y, acc[r][9]);
            acc[r][10] = fmaf(x, e2.z, acc[r][10]);
            acc[r][11] = fmaf(x, e2.w, acc[r][11]);
            acc[r][12] = fmaf(x, e3.x, acc[r][12]);
            acc[r][13] = fmaf(x, e3.y, acc[r][13]);
            acc[r][14] = fmaf(x, e3.z, acc[r][14]);
            acc[r][15] = fmaf(x, e3.w, acc[r][15]);
        }
    }
#pragma unroll
    for (int r = 0; r < 4; ++r)
#pragma unroll
        for (int j = 0; j < 16; ++j) acc[r][j] = warp_reduce_sum64(acc[r][j]);
    if (lane == 0) {
        for (int r = 0; r < 4; ++r)
            for (int j = 0; j < 16; ++j)
                hot[(size_t)(rbase + r) * 16 + j] = acc[r][j];
    }
}

// --------------------- layer 1: LN(16) + h1 = xn @ W1[h]  + attention dots
// block: 512 thr (8 waves = 8 heads), 16 nodes per block; W1 staged in LDS.
__global__ __launch_bounds__(512) void layer1_h(const float* __restrict__ hot,
                                                const float* __restrict__ W1,
                                                const float* __restrict__ a1,
                                                float* __restrict__ h,
                                                float* __restrict__ sa,
                                                float* __restrict__ sb) {
    __shared__ float W1s[H_HEADS * EMB_DIM * D_HEAD]; // 32 KB
    __shared__ float hots[16 * EMB_DIM];
    const int tid = threadIdx.x;
    const int head = tid >> 6, lane = tid & 63;
    for (int i = tid; i < H_HEADS * EMB_DIM * D_HEAD; i += 512) W1s[i] = W1[i];
    const int n0 = blockIdx.x * 16;
    if (tid < 16 * EMB_DIM) hots[tid] = hot[(size_t)n0 * EMB_DIM + tid];
    __syncthreads();
    const float am = a1[head * 128 + lane];
    const float ap = a1[head * 128 + 64 + lane];
    for (int n = 0; n < 16; ++n) {
        float mu = 0.f, m2 = 0.f;
#pragma unroll
        for (int k = 0; k < 16; ++k) { float t = hots[n * 16 + k]; mu += t; m2 += t * t; }
        mu *= (1.f / 16.f); m2 *= (1.f / 16.f);
        float rs = 1.0f / sqrtf(m2 - mu * mu + LN_EPS);
        float hv = 0.f;
#pragma unroll
        for (int k = 0; k < 16; ++k) {
            float xk = (hots[n * 16 + k] - mu) * rs;
            hv = fmaf(xk, W1s[(head * 16 + k) * 64 + lane], hv);
        }
        h[(size_t)(n0 + n) * 512 + tid] = hv;
        float p1 = warp_reduce_sum64(hv * am);
        float p2 = warp_reduce_sum64(hv * ap);
        if (lane == 0) { sa[(n0 + n) * 8 + head] = p1; sb[(n0 + n) * 8 + head] = p2; }
    }
}

// -------------------------- h = X(N,512) @ W[h](512,64), + attention dots
// 64x64 tile, 256 thr (16x16), 4x4 microtile, K-tile 32.
__global__ __launch_bounds__(256) void gemm512(const float* __restrict__ X,
                                               const float* __restrict__ W,
                                               const float* __restrict__ a,
                                               float* __restrict__ h,
                                               float* __restrict__ sa,
                                               float* __restrict__ sb) {
    __shared__ float As[32 * 68];
    __shared__ float Bs[32 * 68];
    const int tid = threadIdx.x;
    const int tx = tid & 15, ty = tid >> 4;
    const int r0 = blockIdx.x * 64;
    const int hd = blockIdx.y;
    const float* Wh = W + (size_t)hd * 512 * 64;
    float acc[4][4];
#pragma unroll
    for (int i = 0; i < 4; ++i)
#pragma unroll
        for (int j = 0; j < 4; ++j) acc[i][j] = 0.f;

    for (int k0 = 0; k0 < 512; k0 += 32) {
#pragma unroll
        for (int it = 0; it < 2; ++it) {
            int flat = tid + it * 256;
            int r = flat >> 3, kq = flat & 7;
            float4 xv = *(const float4*)(X + (size_t)(r0 + r) * 512 + k0 + kq * 4);
            As[(kq * 4 + 0) * 68 + r] = xv.x;
            As[(kq * 4 + 1) * 68 + r] = xv.y;
            As[(kq * 4 + 2) * 68 + r] = xv.z;
            As[(kq * 4 + 3) * 68 + r] = xv.w;
            int k = flat >> 4, nq = flat & 15;
            float4 wv = *(const float4*)(Wh + (size_t)(k0 + k) * 64 + nq * 4);
            *(float4*)(Bs + k * 68 + nq * 4) = wv;
        }
        __syncthreads();
#pragma unroll
        for (int k = 0; k < 32; ++k) {
            float4 av = *(const float4*)(As + k * 68 + ty * 4);
            float4 bv = *(const float4*)(Bs + k * 68 + tx * 4);
            acc[0][0] = fmaf(av.x, bv.x, acc[0][0]);
            acc[0][1] = fmaf(av.x, bv.y, acc[0][1]);
            acc[0][2] = fmaf(av.x, bv.z, acc[0][2]);
            acc[0][3] = fmaf(av.x, bv.w, acc[0][3]);
            acc[1][0] = fmaf(av.y, bv.x, acc[1][0]);
            acc[1][1] = fmaf(av.y, bv.y, acc[1][1]);
            acc[1][2] = fmaf(av.y, bv.z, acc[1][2]);
            acc[1][3] = fmaf(av.y, bv.w, acc[1][3]);
            acc[2][0] = fmaf(av.z, bv.x, acc[2][0]);
            acc[2][1] = fmaf(av.z, bv.y, acc[2][1]);
            acc[2][2] = fmaf(av.z, bv.z, acc[2][2]);
            acc[2][3] = fmaf(av.z, bv.w, acc[2][3]);
            acc[3][0] = fmaf(av.w, bv.x, acc[3][0]);
            acc[3][1] = fmaf(av.w, bv.y, acc[3][1]);
            acc[3][2] = fmaf(av.w, bv.z, acc[3][2]);
            acc[3][3] = fmaf(av.w, bv.w, acc[3][3]);
        }
        __syncthreads();
    }
    float afh[4], ash[4];
#pragma unroll
    for (int j = 0; j < 4; ++j) {
        afh[j] = a[hd * 128 + tx * 4 + j];
        ash[j] = a[hd * 128 + 64 + tx * 4 + j];
    }
#pragma unroll
    for (int i = 0; i < 4; ++i) {
        int r = r0 + ty * 4 + i;
        float4 o; o.x = acc[i][0]; o.y = acc[i][1]; o.z = acc[i][2]; o.w = acc[i][3];
        *(float4*)(h + (size_t)r * 512 + hd * 64 + tx * 4) = o;
        float pa = acc[i][0] * afh[0] + acc[i][1] * afh[1] + acc[i][2] * afh[2] + acc[i][3] * afh[3];
        float pb = acc[i][0] * ash[0] + acc[i][1] * ash[1] + acc[i][2] * ash[2] + acc[i][3] * ash[3];
#pragma unroll
        for (int m = 1; m <= 8; m <<= 1) { pa += __shfl_xor(pa, m, 64); pb += __shfl_xor(pb, m, 64); }
        if (tx == 0) { sa[r * 8 + hd] = pa; sb[r * 8 + hd] = pb; }
    }
}

// ------------------- aggregation: block = node, 512 thr = (head, d)
// FINAL=0: out = LN(elu(num/rowsum))   (N,512)
// FINAL=1: out = log_softmax(elu(LN(num/rowsum)) @ Wo + bo)   (N,40)
// Edge loop: 8-wide chunks, double-buffered (col batch -> batched sb/h gathers),
// ~16 gathers in flight per wave instead of ~2. Padding lanes predicated to e=0.
template <int FINAL>
__global__ __launch_bounds__(512) void aggregate(const float* __restrict__ h,
                                                 const float* __restrict__ sa,
                                                 const float* __restrict__ sb,
                                                 const int* __restrict__ rp,
                                                 const int* __restrict__ col,
                                                 const float* __restrict__ Wo,
                                                 const float* __restrict__ bo,
                                                 float* __restrict__ out) {
    const int r = blockIdx.x;
    const int tid = threadIdx.x;
    const int head = tid >> 6, lane = tid & 63;
    __shared__ float red[8][2];
    __shared__ float bc[2];
    __shared__ float lred[8][NCLASS];
    __shared__ float lbuf[NCLASS];

    const float s1 = sa[r * 8 + head];
    const int i0 = rp[r], i1 = rp[r + 1];
    float acc = 0.f, esum = 0.f;

    if (i0 < i1) {
        float sA[8], hA[8];
        float sB[8] = {0, 0, 0, 0, 0, 0, 0, 0};
        float hB[8] = {0, 0, 0, 0, 0, 0, 0, 0};
        // prologue: batch-load chunk A (padded indices clamped to i0; predicated later)
#pragma unroll
        for (int k = 0; k < 8; ++k) {
            int idx = i0 + k;
            int c = col[idx < i1 ? idx : i0];
            sA[k] = sb[c * 8 + head];
            hA[k] = h[(size_t)c * 512 + tid];
        }
        for (int i = i0; i < i1; i += 8) {
            const int inext = i + 8;
            if (inext < i1) {
                // issue next chunk's address loads + gathers before computing current
#pragma unroll
                for (int k = 0; k < 8; ++k) {
                    int idx = inext + k;
                    int c = col[idx < i1 ? idx : i0];
                    sB[k] = sb[c * 8 + head];
                    hB[k] = h[(size_t)c * 512 + tid];
                }
            }
#pragma unroll
            for (int k = 0; k < 8; ++k) {
                float z = s1 + sA[k];
                float lr = z > 0.f ? z : ALPHA * z;
                float e = __expf(-lr);
                e = (i + k < i1) ? e : 0.f;   // kill padding lanes
                acc = fmaf(e, hA[k], acc);
                esum += e;
            }
#pragma unroll
            for (int k = 0; k < 8; ++k) { sA[k] = sB[k]; hA[k] = hB[k]; }
        }
    }

    float v = acc / esum;
    if (!FINAL) v = v > 0.f ? v : expm1f(v);   // elu before LN (concat layers)
    // ---- LayerNorm over the 512-wide row (block = row)
    float sv = warp_reduce_sum64(v);
    float sv2 = warp_reduce_sum64(v * v);
    if (lane == 0) { red[head][0] = sv; red[head][1] = sv2; }
    __syncthreads();
    if (tid == 0) {
        float s = 0.f, s2s = 0.f;
        for (int w = 0; w < 8; ++w) { s += red[w][0]; s2s += red[w][1]; }
        float mu = s * (1.f / 512.f);
        float var = s2s * (1.f / 512.f) - mu * mu;
        bc[0] = mu; bc[1] = 1.0f / sqrtf(var + LN_EPS);
    }
    __syncthreads();
    v = (v - bc[0]) * bc[1];
    if (!FINAL) {
        out[(size_t)r * 512 + tid] = v;
    } else {
        v = v > 0.f ? v : expm1f(v);           // elu after final LN
        // ---- projection: thread tid owns k=tid; Wo row is 160 B, coalesced
        const float* worow = Wo + tid * NCLASS;
        float pj[NCLASS];
#pragma unroll
        for (int q = 0; q < NCLASS / 4; ++q) {
            float4 wv = *(const float4*)(worow + q * 4);
            pj[q * 4 + 0] = v * wv.x;
            pj[q * 4 + 1] = v * wv.y;
            pj[q * 4 + 2] = v * wv.z;
            pj[q * 4 + 3] = v * wv.w;
        }
#pragma unroll
        for (int j = 0; j < NCLASS; ++j) pj[j] = warp_reduce_sum64(pj[j]);
        if (lane == 0) {
#pragma unroll
            for (int j = 0; j < NCLASS; ++j) lred[head][j] = pj[j];
        }
        __syncthreads();
        if (tid < NCLASS) {
            float s = bo[tid];
            for (int w = 0; w < 8; ++w) s += lred[w][tid];
            lbuf[tid] = s;
        }
        __syncthreads();
        if (head == 0) {
            float l = (lane < NCLASS) ? lbuf[lane] : -3.402823466e38f;
            float m = l;
#pragma unroll
            for (int mm = 32; mm >= 1; mm >>= 1) m = fmaxf(m, __shfl_xor(m, mm, 64));
            float ex = (lane < NCLASS) ? __expf(l - m) : 0.f;
            float ssum = warp_reduce_sum64(ex);
            if (lane < NCLASS) out[(size_t)r * NCLASS + lane] = l - m - logf(ssum);
        }
    }
}

// ---------------------------------------------------------------------------
extern "C" void kernel_launch(void* const* d_in, const int* in_sizes, int n_in,
                              void* d_out, int out_size, void* d_ws, size_t ws_size,
                              hipStream_t stream) {
    const float* x_in = (const float*)d_in[0];
    const float* emb  = (const float*)d_in[1];
    const float* W1   = (const float*)d_in[2];
    const float* a1   = (const float*)d_in[3];
    const float* W2   = (const float*)d_in[4];
    const float* a2   = (const float*)d_in[5];
    const float* Wf   = (const float*)d_in[6];
    const float* af   = (const float*)d_in[7];
    const float* Wo   = (const float*)d_in[8];
    const float* bo   = (const float*)d_in[9];
    const int* erow   = (const int*)d_in[10];
    const int* ecol   = (const int*)d_in[11];
    float* out = (float*)d_out;

    char* w = (char*)d_ws;
    size_t off = 0;
    auto alloc = [&](size_t bytes) -> void* {
        void* p = w + off;
        off = (off + bytes + 255) & ~((size_t)255);
        return p;
    };
    int*   rowptr = (int*)  alloc((size_t)(N_NODES + 1) * sizeof(int));
    float* hot    = (float*)alloc((size_t)N_NODES * EMB_DIM * sizeof(float));
    float* hbuf   = (float*)alloc((size_t)N_NODES * 512 * sizeof(float));
    float* xbuf   = (float*)alloc((size_t)N_NODES * 512 * sizeof(float));
    float* sa     = (float*)alloc((size_t)N_NODES * 8 * sizeof(float));
    float* sb     = (float*)alloc((size_t)N_NODES * 8 * sizeof(float));
    (void)ws_size; (void)in_sizes; (void)n_in; (void)out_size;

    build_rowptr<<<dim3((E_EDGES + 1 + 255) / 256), dim3(256), 0, stream>>>(erow, rowptr);
    gemm_emb<<<dim3(N_NODES / 16), dim3(256), 0, stream>>>(x_in, emb, hot);
    layer1_h<<<dim3(N_NODES / 16), dim3(512), 0, stream>>>(hot, W1, a1, hbuf, sa, sb);
    aggregate<0><<<dim3(N_NODES), dim3(512), 0, stream>>>(hbuf, sa, sb, rowptr, ecol, Wo, bo, xbuf);
    gemm512<<<dim3(N_NODES / 64, H_HEADS), dim3(256), 0, stream>>>(xbuf, W2, a2, hbuf, sa, sb);
    aggregate<0><<<dim3(N_NODES), dim3(512), 0, stream>>>(hbuf, sa, sb, rowptr, ecol, Wo, bo, xbuf);
    gemm512<<<dim3(N_NODES / 64, H_HEADS), dim3(256), 0, stream>>>(xbuf, Wf, af, hbuf, sa, sb);
    aggregate<1><<<dim3(N_NODES), dim3(512), 0, stream>>>(hbuf, sa, sb, rowptr, ecol, Wo, bo, out);
}